// Round 1
// baseline (240.583 us; speedup 1.0000x reference)
//
#include <hip/hip_runtime.h>

// Problem constants (fixed by the reference's setup_inputs)
#define NPEND  128
#define LATENT 256
#define KCOLS  6
#define D0_C   1.0f
#define SEG    32                      // output rows per block
#define SEGS_PER_CHAIN (NPEND / SEG)   // 4
#define ROWS_PER_HALF 5                // ceil(34 / 8)

// One block per 32-row chain segment (+2 halo rows recomputed).
//
// vs previous version:
//  * K^T staged in LDS via coalesced global loads (6 wave-instrs), lanes pull
//    their 24 coefficients with 6 ds_read_b128 — removes the per-lane global
//    K gather (24 x 4B loads at 192B stride = ~64 cache lines per wave instr).
//  * Lane owns latent indices {hl*4+e} and {128+hl*4+e}: every y load and
//    out store is fully contiguous per instruction (512B per half-wave).
//  * __launch_bounds__(256,4) gives the allocator room (<=128 VGPR) so all
//    10 float4 y-loads per lane stay in flight (prev build: 36 VGPR = loads
//    were serialized against their uses).
__global__ __launch_bounds__(256, 4)
void pend_kernel_f32(const float* __restrict__ y,
                     const float* __restrict__ K,
                     float* __restrict__ out)
{
    __shared__ float sKT[3][LATENT];    // K^T, first 3 columns of K
    __shared__ float sR[SEG + 2][3];

    const int tid  = threadIdx.x;
    const int hwid = tid >> 5;          // half-wave id 0..7
    const int hl   = tid & 31;          // lane within half-wave

    const int chain = blockIdx.x >> 2;  // SEGS_PER_CHAIN == 4
    const int seg   = blockIdx.x & 3;
    const int row0  = seg * SEG;
    const int rlo   = (row0 > 0) ? row0 - 1 : 0;
    const int rhi   = (row0 + SEG < NPEND) ? row0 + SEG : NPEND - 1; // inclusive
    const int nrows = rhi - rlo + 1;    // 33 or 34

    // ---- Stage K^T[0:3][:] into LDS, fully coalesced (1536 floats) ----
#pragma unroll
    for (int i = tid; i < LATENT * KCOLS; i += 256) {
        const float v = K[i];
        const int l = i / KCOLS;
        const int c = i - l * KCOLS;
        if (c < 3) sKT[c][l] = v;
    }
    __syncthreads();

    const size_t cbase = (size_t)chain * ((size_t)NPEND * LATENT);
    const int l0 = hl * 4;              // lane's first latent quad

    // ---- Phase 1: issue ALL y loads first (10 float4 in flight/lane) ----
    // Per-instruction addresses are contiguous: half-wave covers 512B.
    float4 va[ROWS_PER_HALF], vb[ROWS_PER_HALF];
#pragma unroll
    for (int j = 0; j < ROWS_PER_HALF; ++j) {
        int i = hwid + 8 * j;
        int row = rlo + ((i < nrows) ? i : (nrows - 1));  // clamp: harmless dup
        const float* yr = y + cbase + (size_t)row * LATENT;
        va[j] = *(const float4*)(yr + l0);
        vb[j] = *(const float4*)(yr + 128 + l0);
    }

    // K fragments from LDS (ds_read_b128 x6) — overlaps with y loads in flight
    const float4 k0a = *(const float4*)&sKT[0][l0];
    const float4 k0b = *(const float4*)&sKT[0][l0 + 128];
    const float4 k1a = *(const float4*)&sKT[1][l0];
    const float4 k1b = *(const float4*)&sKT[1][l0 + 128];
    const float4 k2a = *(const float4*)&sKT[2][l0];
    const float4 k2b = *(const float4*)&sKT[2][l0 + 128];

    // Per-row partial dot products (24 FMAs per row per lane)
    float s0[ROWS_PER_HALF], s1[ROWS_PER_HALF], s2[ROWS_PER_HALF];
#pragma unroll
    for (int j = 0; j < ROWS_PER_HALF; ++j) {
        s0[j] = va[j].x*k0a.x + va[j].y*k0a.y + va[j].z*k0a.z + va[j].w*k0a.w
              + vb[j].x*k0b.x + vb[j].y*k0b.y + vb[j].z*k0b.z + vb[j].w*k0b.w;
        s1[j] = va[j].x*k1a.x + va[j].y*k1a.y + va[j].z*k1a.z + va[j].w*k1a.w
              + vb[j].x*k1b.x + vb[j].y*k1b.y + vb[j].z*k1b.z + vb[j].w*k1b.w;
        s2[j] = va[j].x*k2a.x + va[j].y*k2a.y + va[j].z*k2a.z + va[j].w*k2a.w
              + vb[j].x*k2b.x + vb[j].y*k2b.y + vb[j].z*k2b.z + vb[j].w*k2b.w;
    }

    // 32-wide butterfly reduce: 5 rounds x 15 independent chains
#pragma unroll
    for (int off = 16; off > 0; off >>= 1) {
#pragma unroll
        for (int j = 0; j < ROWS_PER_HALF; ++j) {
            s0[j] += __shfl_down(s0[j], off, 32);
            s1[j] += __shfl_down(s1[j], off, 32);
            s2[j] += __shfl_down(s2[j], off, 32);
        }
    }
    if (hl == 0) {
#pragma unroll
        for (int j = 0; j < ROWS_PER_HALF; ++j) {
            int i = hwid + 8 * j;
            if (i < nrows) {
                sR[i][0] = s0[j]; sR[i][1] = s1[j]; sR[i][2] = s2[j];
            }
        }
    }
    __syncthreads();

    // ---- Phase 2: out3[row] = t(row) - t(row+1); expand by K[:, :3]^T ----
#pragma unroll
    for (int j = 0; j < SEG / 8; ++j) {
        const int i   = hwid + 8 * j;
        const int row = row0 + i;
        const int si  = row - rlo;      // index into sR

        const float rx = sR[si][0], ry = sR[si][1], rz = sR[si][2];
        float px = 0.f, py = 0.f, pz = 0.f;
        if (row > 0) { px = sR[si-1][0]; py = sR[si-1][1]; pz = sR[si-1][2]; }

        const float dx = rx - px, dy = ry - py, dz = rz - pz;
        const float n  = sqrtf(dx*dx + dy*dy + dz*dz);
        const float s  = (n - D0_C) / n;
        float ox = s * dx, oy = s * dy, oz = s * dz;

        if (row < NPEND - 1) {
            const float nx = sR[si+1][0], ny = sR[si+1][1], nz = sR[si+1][2];
            const float ex = nx - rx, ey = ny - ry, ez = nz - rz;
            const float n2 = sqrtf(ex*ex + ey*ey + ez*ez);
            const float t2 = (n2 - D0_C) / n2;
            ox -= t2 * ex; oy -= t2 * ey; oz -= t2 * ez;
        }

        float4 wa, wb;
        wa.x = ox*k0a.x + oy*k1a.x + oz*k2a.x;
        wa.y = ox*k0a.y + oy*k1a.y + oz*k2a.y;
        wa.z = ox*k0a.z + oy*k1a.z + oz*k2a.z;
        wa.w = ox*k0a.w + oy*k1a.w + oz*k2a.w;
        wb.x = ox*k0b.x + oy*k1b.x + oz*k2b.x;
        wb.y = ox*k0b.y + oy*k1b.y + oz*k2b.y;
        wb.z = ox*k0b.z + oy*k1b.z + oz*k2b.z;
        wb.w = ox*k0b.w + oy*k1b.w + oz*k2b.w;

        float* orow = out + cbase + (size_t)row * LATENT;
        *(float4*)(orow + l0)       = wa;
        *(float4*)(orow + 128 + l0) = wb;
    }
}

extern "C" void kernel_launch(void* const* d_in, const int* in_sizes, int n_in,
                              void* d_out, int out_size, void* d_ws, size_t ws_size,
                              hipStream_t stream) {
    // setup_inputs order: y[f32 N*256], z[f32 N] (unused), K[f32 256*6],
    // batch[int32 N] (unused — shape only).
    const float* y = (const float*)d_in[0];
    const float* K = (const float*)d_in[2];
    float* out = (float*)d_out;

    int N  = (n_in > 1 && in_sizes) ? in_sizes[1] : (1024 * NPEND);
    int nb = N / NPEND;
    if (nb <= 0) nb = 1024;
    (void)out_size; (void)d_ws; (void)ws_size;

    pend_kernel_f32<<<nb * SEGS_PER_CHAIN, 256, 0, stream>>>(y, K, out);
}

// Round 2
// 235.990 us; speedup vs baseline: 1.0195x; 1.0195x over previous
//
#include <hip/hip_runtime.h>

// Problem constants (fixed by the reference's setup_inputs)
#define NPEND  128
#define LATENT 256
#define KCOLS  6
#define D0_C   1.0f
#define SEG    32                      // output rows per block
#define SEGS_PER_CHAIN (NPEND / SEG)   // 4
#define ROWS_PER_HALF 5                // ceil(34 / 8)

// One block per 32-row chain segment (+2 halo rows recomputed).
//
// vs previous version:
//  * __builtin_amdgcn_sched_barrier(0) between the load batch and the FMA
//    batch. Previous builds had VGPR_Count=40: the scheduler sank each load
//    into its use site -> ~5 sequential HBM round trips per wave. The hard
//    fence forces all 10 global_load_dwordx4 + 6 ds_read_b128 to issue
//    before any use (one ~900cyc wait instead of five). Expect VGPR ~90.
//  * K staging rewritten conflict-free: thread tid loads K[tid][0..2] and
//    writes sKT[c][tid] (bank = tid%32). The previous i/6 scheme put 3
//    threads with the same l on one bank -> 393K SQ_LDS_BANK_CONFLICT.
__global__ __launch_bounds__(256, 4)
void pend_kernel_f32(const float* __restrict__ y,
                     const float* __restrict__ K,
                     float* __restrict__ out)
{
    __shared__ float sKT[3][LATENT];    // K^T, first 3 columns of K
    __shared__ float sR[SEG + 2][3];

    const int tid  = threadIdx.x;
    const int hwid = tid >> 5;          // half-wave id 0..7
    const int hl   = tid & 31;          // lane within half-wave

    const int chain = blockIdx.x >> 2;  // SEGS_PER_CHAIN == 4
    const int seg   = blockIdx.x & 3;
    const int row0  = seg * SEG;
    const int rlo   = (row0 > 0) ? row0 - 1 : 0;
    const int rhi   = (row0 + SEG < NPEND) ? row0 + SEG : NPEND - 1; // inclusive
    const int nrows = rhi - rlo + 1;    // 33 or 34

    // ---- Stage K^T[0:3][:] into LDS, conflict-free ----
    // thread tid owns latent index tid: 3 scalar global loads (6KB matrix,
    // L2-resident), LDS writes hit bank tid%32 -> no conflicts.
    {
        const float ka = K[tid * KCOLS + 0];
        const float kb = K[tid * KCOLS + 1];
        const float kc = K[tid * KCOLS + 2];
        sKT[0][tid] = ka;
        sKT[1][tid] = kb;
        sKT[2][tid] = kc;
    }
    __syncthreads();

    const size_t cbase = (size_t)chain * ((size_t)NPEND * LATENT);
    const int l0 = hl * 4;              // lane's first latent quad

    // ---- Phase 1: issue ALL y loads (10 float4/lane) + K ds_reads ----
    float4 va[ROWS_PER_HALF], vb[ROWS_PER_HALF];
#pragma unroll
    for (int j = 0; j < ROWS_PER_HALF; ++j) {
        int i = hwid + 8 * j;
        int row = rlo + ((i < nrows) ? i : (nrows - 1));  // clamp: harmless dup
        const float* yr = y + cbase + (size_t)row * LATENT;
        va[j] = *(const float4*)(yr + l0);
        vb[j] = *(const float4*)(yr + 128 + l0);
    }

    const float4 k0a = *(const float4*)&sKT[0][l0];
    const float4 k0b = *(const float4*)&sKT[0][l0 + 128];
    const float4 k1a = *(const float4*)&sKT[1][l0];
    const float4 k1b = *(const float4*)&sKT[1][l0 + 128];
    const float4 k2a = *(const float4*)&sKT[2][l0];
    const float4 k2b = *(const float4*)&sKT[2][l0 + 128];

    // HARD FENCE: nothing crosses. All 10 global loads + 6 ds_reads are now
    // in flight before the first FMA -> single vmcnt/lgkmcnt wait.
    __builtin_amdgcn_sched_barrier(0);

    // Per-row partial dot products (24 FMAs per row per lane)
    float s0[ROWS_PER_HALF], s1[ROWS_PER_HALF], s2[ROWS_PER_HALF];
#pragma unroll
    for (int j = 0; j < ROWS_PER_HALF; ++j) {
        s0[j] = va[j].x*k0a.x + va[j].y*k0a.y + va[j].z*k0a.z + va[j].w*k0a.w
              + vb[j].x*k0b.x + vb[j].y*k0b.y + vb[j].z*k0b.z + vb[j].w*k0b.w;
        s1[j] = va[j].x*k1a.x + va[j].y*k1a.y + va[j].z*k1a.z + va[j].w*k1a.w
              + vb[j].x*k1b.x + vb[j].y*k1b.y + vb[j].z*k1b.z + vb[j].w*k1b.w;
        s2[j] = va[j].x*k2a.x + va[j].y*k2a.y + va[j].z*k2a.z + va[j].w*k2a.w
              + vb[j].x*k2b.x + vb[j].y*k2b.y + vb[j].z*k2b.z + vb[j].w*k2b.w;
    }

    // 32-wide butterfly reduce: 5 rounds x 15 independent chains
#pragma unroll
    for (int off = 16; off > 0; off >>= 1) {
#pragma unroll
        for (int j = 0; j < ROWS_PER_HALF; ++j) {
            s0[j] += __shfl_down(s0[j], off, 32);
            s1[j] += __shfl_down(s1[j], off, 32);
            s2[j] += __shfl_down(s2[j], off, 32);
        }
    }
    if (hl == 0) {
#pragma unroll
        for (int j = 0; j < ROWS_PER_HALF; ++j) {
            int i = hwid + 8 * j;
            if (i < nrows) {
                sR[i][0] = s0[j]; sR[i][1] = s1[j]; sR[i][2] = s2[j];
            }
        }
    }
    __syncthreads();

    // ---- Phase 2: out3[row] = t(row) - t(row+1); expand by K[:, :3]^T ----
#pragma unroll
    for (int j = 0; j < SEG / 8; ++j) {
        const int i   = hwid + 8 * j;
        const int row = row0 + i;
        const int si  = row - rlo;      // index into sR

        const float rx = sR[si][0], ry = sR[si][1], rz = sR[si][2];
        float px = 0.f, py = 0.f, pz = 0.f;
        if (row > 0) { px = sR[si-1][0]; py = sR[si-1][1]; pz = sR[si-1][2]; }

        const float dx = rx - px, dy = ry - py, dz = rz - pz;
        const float n  = sqrtf(dx*dx + dy*dy + dz*dz);
        const float s  = (n - D0_C) / n;
        float ox = s * dx, oy = s * dy, oz = s * dz;

        if (row < NPEND - 1) {
            const float nx = sR[si+1][0], ny = sR[si+1][1], nz = sR[si+1][2];
            const float ex = nx - rx, ey = ny - ry, ez = nz - rz;
            const float n2 = sqrtf(ex*ex + ey*ey + ez*ez);
            const float t2 = (n2 - D0_C) / n2;
            ox -= t2 * ex; oy -= t2 * ey; oz -= t2 * ez;
        }

        float4 wa, wb;
        wa.x = ox*k0a.x + oy*k1a.x + oz*k2a.x;
        wa.y = ox*k0a.y + oy*k1a.y + oz*k2a.y;
        wa.z = ox*k0a.z + oy*k1a.z + oz*k2a.z;
        wa.w = ox*k0a.w + oy*k1a.w + oz*k2a.w;
        wb.x = ox*k0b.x + oy*k1b.x + oz*k2b.x;
        wb.y = ox*k0b.y + oy*k1b.y + oz*k2b.y;
        wb.z = ox*k0b.z + oy*k1b.z + oz*k2b.z;
        wb.w = ox*k0b.w + oy*k1b.w + oz*k2b.w;

        float* orow = out + cbase + (size_t)row * LATENT;
        *(float4*)(orow + l0)       = wa;
        *(float4*)(orow + 128 + l0) = wb;
    }
}

extern "C" void kernel_launch(void* const* d_in, const int* in_sizes, int n_in,
                              void* d_out, int out_size, void* d_ws, size_t ws_size,
                              hipStream_t stream) {
    // setup_inputs order: y[f32 N*256], z[f32 N] (unused), K[f32 256*6],
    // batch[int32 N] (unused — shape only).
    const float* y = (const float*)d_in[0];
    const float* K = (const float*)d_in[2];
    float* out = (float*)d_out;

    int N  = (n_in > 1 && in_sizes) ? in_sizes[1] : (1024 * NPEND);
    int nb = N / NPEND;
    if (nb <= 0) nb = 1024;
    (void)out_size; (void)d_ws; (void)ws_size;

    pend_kernel_f32<<<nb * SEGS_PER_CHAIN, 256, 0, stream>>>(y, K, out);
}